// Round 5
// baseline (417.680 us; speedup 1.0000x reference)
//
#include <hip/hip_runtime.h>

typedef __attribute__((ext_vector_type(8))) __bf16 bf16x8;
typedef __attribute__((ext_vector_type(4))) float f32x4;

#define N_ 1024
#define C_ 64
#define BP_ 48

static __device__ __forceinline__ unsigned short f2bf(float f) {
    __bf16 b = (__bf16)f;
    return __builtin_bit_cast(unsigned short, b);
}
static __device__ __forceinline__ unsigned int pack2(float a, float b) {
    return (unsigned int)f2bf(a) | ((unsigned int)f2bf(b) << 16);
}

// ---------------------------------------------------------------------------
// K1: v1/v2 fold of W_emb, s1/s2 per node, per-wave max(s2) -> M2part, and
// bf16 transpose xP[bp][c][j'] where j' is the per-64-chunk fragment
// permutation used by K2's MFMA: element (s*32+q*8+e) of a chunk holds
// source j = g*16 + q*4 + (e&3), g = 2s+(e>>2).  This makes K2's A-operand
// (computed in-register) and B-operand (this array) agree lane-for-lane.
// grid (16 j-tiles, 48 bp), block 256 (4 waves).
// ---------------------------------------------------------------------------
__global__ __launch_bounds__(256) void gat_pre(
    const float* __restrict__ x, const float* __restrict__ Wemb,
    const float* __restrict__ a1, const float* __restrict__ a2,
    float* __restrict__ s1g, float* __restrict__ s2g,
    unsigned short* __restrict__ xP, float* __restrict__ M2part)
{
    __shared__ float xs[64][65];
    __shared__ float vs[2][64];
    const int t = threadIdx.x, l = t & 63, w = t >> 6;
    const int j0 = blockIdx.x * 64;
    const int bp = blockIdx.y;

    if (w == 0) {   // v1[c]=sum_h a1[h]*W_emb[h][c]  (x_emb folds away)
        float v1 = 0.f, v2 = 0.f;
        #pragma unroll 8
        for (int h = 0; h < 64; ++h) {
            float we = Wemb[h * 64 + l];
            v1 = fmaf(a1[h], we, v1);
            v2 = fmaf(a2[h], we, v2);
        }
        vs[0][l] = v1; vs[1][l] = v2;
    }
    const float* xb = x + ((size_t)bp * N_ + j0) * C_;
    #pragma unroll
    for (int it = 0; it < 16; ++it)
        xs[it * 4 + w][l] = xb[(it * 4 + w) * C_ + l];
    __syncthreads();

    const int jr = t >> 2, c0 = (t & 3) * 16;
    float p1 = 0.f, p2 = 0.f;
    #pragma unroll
    for (int k = 0; k < 16; ++k) {
        float xv = xs[jr][c0 + k];
        p1 = fmaf(xv, vs[0][c0 + k], p1);
        p2 = fmaf(xv, vs[1][c0 + k], p2);
    }
    p1 += __shfl_xor(p1, 1); p1 += __shfl_xor(p1, 2);
    p2 += __shfl_xor(p2, 1); p2 += __shfl_xor(p2, 2);
    if ((l & 3) == 0) {
        s1g[bp * N_ + j0 + jr] = p1;
        s2g[bp * N_ + j0 + jr] = p2;
    }
    float m = p2;
    m = fmaxf(m, __shfl_xor(m, 4));
    m = fmaxf(m, __shfl_xor(m, 8));
    m = fmaxf(m, __shfl_xor(m, 16));
    m = fmaxf(m, __shfl_xor(m, 32));
    if (l == 0) M2part[bp * 64 + blockIdx.x * 4 + w] = m;

    // permuted transpose store: source j_local = part*16 + 4m + i  ->
    // dest  d = (part>>1)*32 + (part&1)*4 + m*8 + i   (within this 64-chunk)
    const int c = t >> 2, part = t & 3;
    unsigned short* dstb = xP + (size_t)bp * C_ * N_ + (size_t)c * N_ + j0 +
                           (part >> 1) * 32 + (part & 1) * 4;
    #pragma unroll
    for (int m_ = 0; m_ < 4; ++m_) {
        unsigned int lo = pack2(xs[part * 16 + 4 * m_ + 0][c],
                                xs[part * 16 + 4 * m_ + 1][c]);
        unsigned int hi = pack2(xs[part * 16 + 4 * m_ + 2][c],
                                xs[part * 16 + 4 * m_ + 3][c]);
        *(uint2*)&dstb[m_ * 8] = make_uint2(lo, hi);
    }
}

// ---------------------------------------------------------------------------
// K2 v6: chain-collapse.  R1-R4 showed the ~130us plateau is neither
// occupancy (12 vs 16 w/CU identical) nor load latency (reg prefetch
// identical) -> it's the per-chunk SERIAL chain exp->pack->ds_write->
// ds_read->MFMA (~600cy dependent).  Two structural fixes:
//  (1) A in {0,1}  =>  e = A * exp(z-mv): the exp block is A-INDEPENDENT
//      and fills the load-latency shadow; A's dependent ops = 1 fmul.
//  (2) re-map work so lane (i15,q) computes ITS OWN MFMA fragment:
//      row i15, j = g*16+q*4+r (g=2s+(e>>2), r=e&3) -- a per-32-window
//      permutation applied to BOTH operands (xP pre-permuted in K1).
//      P goes register->MFMA; the P LDS round-trip is deleted.
//      A loads / outA stores become dense 64B runs per 4-lane group.
// One row per lane also deletes the s1 shuffles and 4-row sr machinery.
// grid (16,48), block 256 (4 indep waves), launch_bounds(256,3), ~120 VGPR.
// ---------------------------------------------------------------------------
__global__ __launch_bounds__(256, 3) void gat_fused(
    const float* __restrict__ Ag, float* __restrict__ outA,
    const unsigned short* __restrict__ xP,
    const float* __restrict__ s1g, const float* __restrict__ s2g,
    const float* __restrict__ M2part,
    const float* __restrict__ Wlin, float* __restrict__ out)
{
    __shared__ unsigned short aggLDS[4][16][72]; // 9 KB  epilogue only (pad 8)
    __shared__ float s2lds[1024];                // 4 KB  s2 row, block-shared
    __shared__ float lsLDS[4][16];               // 256 B per-wave row sums

    const int t = threadIdx.x, l = t & 63, w = t >> 6;
    const int i15 = l & 15, q = l >> 4;
    const int bp = blockIdx.y;
    const int ibase = blockIdx.x * 64 + w * 16;

    // stage s2 (1024 f32) to LDS, block-wide
    *(f32x4*)&s2lds[4 * t] = *(const f32x4*)&s2g[bp * N_ + 4 * t];

    float m2v = M2part[bp * 64 + l];
    #pragma unroll
    for (int off = 32; off >= 1; off >>= 1)
        m2v = fmaxf(m2v, __shfl_xor(m2v, off));
    const float M2 = m2v;
    // this lane owns output row (ibase + i15) exclusively
    const float s1_l = s1g[bp * N_ + ibase + i15];
    const float zr = s1_l + M2;
    const float mv = fmaxf(zr, 0.01f * zr);   // global max_j leaky(s1+s2j)

    __syncthreads();   // s2lds ready (only barrier before epilogue)

    // lane base pointers: row (ibase+i15), col q*4 (+g*16 within chunk)
    const float* Arow = Ag + ((size_t)bp * N_ + ibase + i15) * N_ + q * 4;
    float* oArow = outA + ((size_t)bp * N_ + ibase + i15) * N_ + q * 4;
    const unsigned short* xProw = xP + (size_t)bp * C_ * N_ + (size_t)i15 * N_ + q * 8;

    f32x4 acc[4] = {};          // D: row q*4+r, col nt*16+i15
    float ls = 0.f;             // partial row-sum of row i15 (this lane's j's)

    f32x4 Aa[4], Ab[4];         // A double-buffer: [g] = cols g*16+q*4+0..3
    bf16x8 X[8];                // xP fragments [s*4+nt], single-buffered

#define LOADX(kk) do {                                                        \
    _Pragma("unroll")                                                         \
    for (int nt = 0; nt < 4; ++nt)                                            \
        _Pragma("unroll")                                                     \
        for (int s = 0; s < 2; ++s)                                           \
            X[s * 4 + nt] = *(const bf16x8*)&xProw[(size_t)nt * 16 * N_ +     \
                                                   (kk) * 64 + s * 32];       \
    } while (0)

#define LOADA(Ax, kk) do {                                                    \
    const float* _p = Arow + (kk) * 64;                                       \
    _Pragma("unroll")                                                         \
    for (int g = 0; g < 4; ++g)                                               \
        Ax[g] = __builtin_nontemporal_load((const f32x4*)(_p + g * 16));      \
    } while (0)

// consume chunk kk: Ac loaded >=1 chunk ago, X loaded at this chunk's start
#define CONSUME(Ac, kk) do {                                                  \
    const int jrel = (kk) * 64;                                               \
    /* E block: A-independent, fills the latency shadow */                    \
    f32x4 Ev[4];                                                              \
    _Pragma("unroll")                                                         \
    for (int g = 0; g < 4; ++g) {                                             \
        const f32x4 s2v = *(const f32x4*)&s2lds[jrel + g * 16 + q * 4];       \
        _Pragma("unroll")                                                     \
        for (int r = 0; r < 4; ++r) {                                         \
            float zz = s1_l + s2v[r];                                         \
            zz = fmaxf(zz, 0.01f * zz);                                       \
            Ev[g][r] = __expf(zz - mv);                                       \
        }                                                                     \
    }                                                                         \
    /* A-dependent part: passthrough store + 1 fmul per element */            \
    _Pragma("unroll")                                                         \
    for (int g = 0; g < 4; ++g)                                               \
        __builtin_nontemporal_store(Ac[g], (f32x4*)(oArow + jrel + g * 16));  \
    f32x4 P[4];                                                               \
    _Pragma("unroll")                                                         \
    for (int g = 0; g < 4; ++g) {                                             \
        _Pragma("unroll")                                                     \
        for (int r = 0; r < 4; ++r) {                                         \
            P[g][r] = Ac[g][r] * Ev[g][r];                                    \
            ls += P[g][r];                                                    \
        }                                                                     \
    }                                                                         \
    uint4 u0 = make_uint4(pack2(P[0][0], P[0][1]), pack2(P[0][2], P[0][3]),   \
                          pack2(P[1][0], P[1][1]), pack2(P[1][2], P[1][3]));  \
    uint4 u1 = make_uint4(pack2(P[2][0], P[2][1]), pack2(P[2][2], P[2][3]),   \
                          pack2(P[3][0], P[3][1]), pack2(P[3][2], P[3][3]));  \
    bf16x8 af0 = __builtin_bit_cast(bf16x8, u0);                              \
    bf16x8 af1 = __builtin_bit_cast(bf16x8, u1);                              \
    _Pragma("unroll")                                                         \
    for (int nt = 0; nt < 4; ++nt)                                            \
        acc[nt] = __builtin_amdgcn_mfma_f32_16x16x32_bf16(af0, X[nt],         \
                                                          acc[nt], 0, 0, 0);  \
    _Pragma("unroll")                                                         \
    for (int nt = 0; nt < 4; ++nt)                                            \
        acc[nt] = __builtin_amdgcn_mfma_f32_16x16x32_bf16(af1, X[4 + nt],     \
                                                          acc[nt], 0, 0, 0);  \
    } while (0)

    // prime A chunk 0
    LOADA(Aa, 0);
    #pragma unroll 1
    for (int k = 0; k < 16; k += 2) {
        LOADX(k);                      // loads first: waits never drain stores
        LOADA(Ab, k + 1);
        CONSUME(Aa, k);
        LOADX(k + 1);
        if (k + 2 < 16) LOADA(Aa, k + 2);
        CONSUME(Ab, k + 1);
    }
#undef LOADX
#undef LOADA
#undef CONSUME

    // row-sum: lane has partial of row i15; combine across the 4 q-groups
    ls += __shfl_xor(ls, 16);
    ls += __shfl_xor(ls, 32);
    if (q == 0) lsLDS[w][i15] = ls;
    const f32x4 lsq = *(const f32x4*)&lsLDS[w][4 * q];   // rows 4q..4q+3

    // ---- epilogue: agg = acc/l, LDS round-trip to A-layout, @W_lin^T, sigmoid
    unsigned short* aggl = &aggLDS[w][0][0];   // stride 72
    #pragma unroll
    for (int nt = 0; nt < 4; ++nt)
        #pragma unroll
        for (int r = 0; r < 4; ++r)
            aggl[(q * 4 + r) * 72 + nt * 16 + i15] = f2bf(acc[nt][r] / lsq[r]);

    f32x4 d2[4] = {};
    #pragma unroll
    for (int s = 0; s < 2; ++s) {
        bf16x8 af = *(const bf16x8*)&aggl[i15 * 72 + s * 32 + q * 8];
        #pragma unroll
        for (int nt = 0; nt < 4; ++nt) {
            const float* wp = Wlin + (size_t)(nt * 16 + i15) * C_ + s * 32 + q * 8;
            f32x4 w0 = *(const f32x4*)wp;
            f32x4 w1 = *(const f32x4*)(wp + 4);
            bf16x8 bfr;
            #pragma unroll
            for (int jj = 0; jj < 4; ++jj) { bfr[jj] = (__bf16)w0[jj]; bfr[4 + jj] = (__bf16)w1[jj]; }
            d2[nt] = __builtin_amdgcn_mfma_f32_16x16x32_bf16(af, bfr, d2[nt], 0, 0, 0);
        }
    }
    float* orow = out + ((size_t)bp * N_ + ibase) * C_;
    #pragma unroll
    for (int nt = 0; nt < 4; ++nt)
        #pragma unroll
        for (int r = 0; r < 4; ++r)
            orow[(size_t)(q * 4 + r) * C_ + nt * 16 + i15] =
                1.f / (1.f + __expf(-d2[nt][r]));
}

extern "C" void kernel_launch(void* const* d_in, const int* in_sizes, int n_in,
                              void* d_out, int out_size, void* d_ws, size_t ws_size,
                              hipStream_t stream) {
    const float* x    = (const float*)d_in[0];
    const float* Ag   = (const float*)d_in[1];
    const float* Wemb = (const float*)d_in[2];
    const float* a1   = (const float*)d_in[3];
    const float* a2   = (const float*)d_in[4];
    const float* Wlin = (const float*)d_in[5];
    float* out  = (float*)d_out;
    float* outA = out + (size_t)BP_ * N_ * C_;   // tuple output #2: A passthrough

    // ws layout (~6.7 MB total)
    float* s1g = (float*)d_ws;                               // 48K f32
    float* s2g = s1g + BP_ * N_;                             // 48K f32
    float* M2part = s2g + BP_ * N_;                          // 48*64 f32
    unsigned short* xP = (unsigned short*)(M2part + BP_ * 64);   // 6.3MB bf16

    gat_pre<<<dim3(16, BP_), dim3(256), 0, stream>>>(x, Wemb, a1, a2,
                                                     s1g, s2g, xP, M2part);
    gat_fused<<<dim3(16, BP_), dim3(256), 0, stream>>>(Ag, outA, xP, s1g, s2g,
                                                       M2part, Wlin, out);
}

// Round 6
// 396.022 us; speedup vs baseline: 1.0547x; 1.0547x over previous
//
#include <hip/hip_runtime.h>

typedef __attribute__((ext_vector_type(8))) __bf16 bf16x8;
typedef __attribute__((ext_vector_type(4))) float f32x4;

#define N_ 1024
#define C_ 64
#define BP_ 48

static __device__ __forceinline__ unsigned short f2bf(float f) {
    __bf16 b = (__bf16)f;
    return __builtin_bit_cast(unsigned short, b);
}
static __device__ __forceinline__ unsigned int pack2(float a, float b) {
    return (unsigned int)f2bf(a) | ((unsigned int)f2bf(b) << 16);
}

// ---------------------------------------------------------------------------
// K1: v1/v2 fold of W_emb, s1/s2 per node, per-wave max(s2) -> M2part, and
// bf16 transpose xP[bp][c][j'] where j' is the per-64-chunk fragment
// permutation used by K2's MFMA: element (s*32+q*8+e) of a chunk holds
// source j = g*16 + q*4 + (e&3), g = 2s+(e>>2).  This makes K2's A-operand
// (computed in-register) and B-operand (this array) agree lane-for-lane.
// grid (16 j-tiles, 48 bp), block 256 (4 waves).
// ---------------------------------------------------------------------------
__global__ __launch_bounds__(256) void gat_pre(
    const float* __restrict__ x, const float* __restrict__ Wemb,
    const float* __restrict__ a1, const float* __restrict__ a2,
    float* __restrict__ s1g, float* __restrict__ s2g,
    unsigned short* __restrict__ xP, float* __restrict__ M2part)
{
    __shared__ float xs[64][65];
    __shared__ float vs[2][64];
    const int t = threadIdx.x, l = t & 63, w = t >> 6;
    const int j0 = blockIdx.x * 64;
    const int bp = blockIdx.y;

    if (w == 0) {   // v1[c]=sum_h a1[h]*W_emb[h][c]  (x_emb folds away)
        float v1 = 0.f, v2 = 0.f;
        #pragma unroll 8
        for (int h = 0; h < 64; ++h) {
            float we = Wemb[h * 64 + l];
            v1 = fmaf(a1[h], we, v1);
            v2 = fmaf(a2[h], we, v2);
        }
        vs[0][l] = v1; vs[1][l] = v2;
    }
    const float* xb = x + ((size_t)bp * N_ + j0) * C_;
    #pragma unroll
    for (int it = 0; it < 16; ++it)
        xs[it * 4 + w][l] = xb[(it * 4 + w) * C_ + l];
    __syncthreads();

    const int jr = t >> 2, c0 = (t & 3) * 16;
    float p1 = 0.f, p2 = 0.f;
    #pragma unroll
    for (int k = 0; k < 16; ++k) {
        float xv = xs[jr][c0 + k];
        p1 = fmaf(xv, vs[0][c0 + k], p1);
        p2 = fmaf(xv, vs[1][c0 + k], p2);
    }
    p1 += __shfl_xor(p1, 1); p1 += __shfl_xor(p1, 2);
    p2 += __shfl_xor(p2, 1); p2 += __shfl_xor(p2, 2);
    if ((l & 3) == 0) {
        s1g[bp * N_ + j0 + jr] = p1;
        s2g[bp * N_ + j0 + jr] = p2;
    }
    float m = p2;
    m = fmaxf(m, __shfl_xor(m, 4));
    m = fmaxf(m, __shfl_xor(m, 8));
    m = fmaxf(m, __shfl_xor(m, 16));
    m = fmaxf(m, __shfl_xor(m, 32));
    if (l == 0) M2part[bp * 64 + blockIdx.x * 4 + w] = m;

    // permuted transpose store: source j_local = part*16 + 4m + i  ->
    // dest  d = (part>>1)*32 + (part&1)*4 + m*8 + i   (within this 64-chunk)
    const int c = t >> 2, part = t & 3;
    unsigned short* dstb = xP + (size_t)bp * C_ * N_ + (size_t)c * N_ + j0 +
                           (part >> 1) * 32 + (part & 1) * 4;
    #pragma unroll
    for (int m_ = 0; m_ < 4; ++m_) {
        unsigned int lo = pack2(xs[part * 16 + 4 * m_ + 0][c],
                                xs[part * 16 + 4 * m_ + 1][c]);
        unsigned int hi = pack2(xs[part * 16 + 4 * m_ + 2][c],
                                xs[part * 16 + 4 * m_ + 3][c]);
        *(uint2*)&dstb[m_ * 8] = make_uint2(lo, hi);
    }
}

// ---------------------------------------------------------------------------
// K2 v7: v6 + PINNED issue order.  R5's VGPR_Count=64 proved the compiler
// collapsed every source-level pipeline (R1/R3/R4/R5 all ~137us): loads
// sunk to uses, so each chunk's counted load-wait also drained the
// previous chunk's (NT, HBM-ack) stores via in-order vmcnt.
// Fix: sched_barrier(0) fences pin per-iter order to
//   [issue X(k+1)+A(k+1)] | [E-block VALU] | [P=A*E, stores(k), MFMA]
// so loads are ALWAYS older than the stores that follow -> waiting for
// chunk-k loads never waits any store; stores get >=1 chunk to retire.
// Stores/loads back to PLAIN (L2-ack, line-merging in L2).
// grid (16,48), block 256 (4 indep waves), launch_bounds(256,3) cap 170.
// ---------------------------------------------------------------------------
#define SB() __builtin_amdgcn_sched_barrier(0)

__global__ __launch_bounds__(256, 3) void gat_fused(
    const float* __restrict__ Ag, float* __restrict__ outA,
    const unsigned short* __restrict__ xP,
    const float* __restrict__ s1g, const float* __restrict__ s2g,
    const float* __restrict__ M2part,
    const float* __restrict__ Wlin, float* __restrict__ out)
{
    __shared__ unsigned short aggLDS[4][16][72]; // 9 KB  epilogue only (pad 8)
    __shared__ float s2lds[1024];                // 4 KB  s2 row, block-shared
    __shared__ float lsLDS[4][16];               // 256 B per-wave row sums

    const int t = threadIdx.x, l = t & 63, w = t >> 6;
    const int i15 = l & 15, q = l >> 4;
    const int bp = blockIdx.y;
    const int ibase = blockIdx.x * 64 + w * 16;

    // stage s2 (1024 f32) to LDS, block-wide
    *(f32x4*)&s2lds[4 * t] = *(const f32x4*)&s2g[bp * N_ + 4 * t];

    float m2v = M2part[bp * 64 + l];
    #pragma unroll
    for (int off = 32; off >= 1; off >>= 1)
        m2v = fmaxf(m2v, __shfl_xor(m2v, off));
    const float M2 = m2v;
    // this lane owns output row (ibase + i15) exclusively
    const float s1_l = s1g[bp * N_ + ibase + i15];
    const float zr = s1_l + M2;
    const float mv = fmaxf(zr, 0.01f * zr);   // global max_j leaky(s1+s2j)

    __syncthreads();   // s2lds ready (only barrier before epilogue)

    // lane base pointers: row (ibase+i15), col q*4 (+g*16 within chunk)
    const float* Arow = Ag + ((size_t)bp * N_ + ibase + i15) * N_ + q * 4;
    float* oArow = outA + ((size_t)bp * N_ + ibase + i15) * N_ + q * 4;
    const unsigned short* xProw = xP + (size_t)bp * C_ * N_ + (size_t)i15 * N_ + q * 8;

    f32x4 acc[4] = {};          // D: row q*4+r, col nt*16+i15
    float ls = 0.f;             // partial row-sum of row i15 (this lane's j's)

    f32x4 Aa[4], Ab[4];         // A double-buffer: [g] = cols g*16+q*4+0..3
    bf16x8 Xa[8], Xb[8];        // xP fragment double-buffer [s*4+nt]

#define LOADX(Xc, kk) do {                                                    \
    _Pragma("unroll")                                                         \
    for (int nt = 0; nt < 4; ++nt)                                            \
        _Pragma("unroll")                                                     \
        for (int s = 0; s < 2; ++s)                                           \
            Xc[s * 4 + nt] = *(const bf16x8*)&xProw[(size_t)nt * 16 * N_ +    \
                                                    (kk) * 64 + s * 32];      \
    } while (0)

#define LOADA(Ax, kk) do {                                                    \
    const float* _p = Arow + (kk) * 64;                                       \
    _Pragma("unroll")                                                         \
    for (int g = 0; g < 4; ++g)                                               \
        Ax[g] = *(const f32x4*)(_p + g * 16);                                 \
    } while (0)

// consume chunk kk from Ac (A regs) and Xc (xP regs), both loaded >=1 iter ago
#define CONSUME(Ac, Xc, kk) do {                                              \
    const int jrel = (kk) * 64;                                               \
    /* E block: A-independent VALU, runs while chunk-kk loads are in flight */\
    f32x4 Ev[4];                                                              \
    _Pragma("unroll")                                                         \
    for (int g = 0; g < 4; ++g) {                                             \
        const f32x4 s2v = *(const f32x4*)&s2lds[jrel + g * 16 + q * 4];       \
        _Pragma("unroll")                                                     \
        for (int r = 0; r < 4; ++r) {                                         \
            float zz = s1_l + s2v[r];                                         \
            zz = fmaxf(zz, 0.01f * zz);                                       \
            Ev[g][r] = __expf(zz - mv);                                       \
        }                                                                     \
    }                                                                         \
    SB();                                                                     \
    /* A-dependent tail: 1 fmul/elem, passthrough store, pack, MFMA */        \
    f32x4 P[4];                                                               \
    _Pragma("unroll")                                                         \
    for (int g = 0; g < 4; ++g) {                                             \
        *(f32x4*)(oArow + jrel + g * 16) = Ac[g];                             \
        _Pragma("unroll")                                                     \
        for (int r = 0; r < 4; ++r) {                                         \
            P[g][r] = Ac[g][r] * Ev[g][r];                                    \
            ls += P[g][r];                                                    \
        }                                                                     \
    }                                                                         \
    uint4 u0 = make_uint4(pack2(P[0][0], P[0][1]), pack2(P[0][2], P[0][3]),   \
                          pack2(P[1][0], P[1][1]), pack2(P[1][2], P[1][3]));  \
    uint4 u1 = make_uint4(pack2(P[2][0], P[2][1]), pack2(P[2][2], P[2][3]),   \
                          pack2(P[3][0], P[3][1]), pack2(P[3][2], P[3][3]));  \
    bf16x8 af0 = __builtin_bit_cast(bf16x8, u0);                              \
    bf16x8 af1 = __builtin_bit_cast(bf16x8, u1);                              \
    _Pragma("unroll")                                                         \
    for (int nt = 0; nt < 4; ++nt)                                            \
        acc[nt] = __builtin_amdgcn_mfma_f32_16x16x32_bf16(af0, Xc[nt],        \
                                                          acc[nt], 0, 0, 0);  \
    _Pragma("unroll")                                                         \
    for (int nt = 0; nt < 4; ++nt)                                            \
        acc[nt] = __builtin_amdgcn_mfma_f32_16x16x32_bf16(af1, Xc[4 + nt],    \
                                                          acc[nt], 0, 0, 0);  \
    } while (0)

    // prime chunk 0
    LOADX(Xa, 0); LOADA(Aa, 0);
    #pragma unroll 1
    for (int k = 0; k < 16; k += 2) {
        SB();
        LOADX(Xb, k + 1); LOADA(Ab, k + 1);   // issue BEFORE any chunk-k store
        SB();
        CONSUME(Aa, Xa, k);
        SB();
        if (k + 2 < 16) { LOADX(Xa, k + 2); LOADA(Aa, k + 2); }
        SB();
        CONSUME(Ab, Xb, k + 1);
    }
    SB();
#undef LOADX
#undef LOADA
#undef CONSUME

    // row-sum: lane has partial of row i15; combine across the 4 q-groups
    ls += __shfl_xor(ls, 16);
    ls += __shfl_xor(ls, 32);
    if (q == 0) lsLDS[w][i15] = ls;
    const f32x4 lsq = *(const f32x4*)&lsLDS[w][4 * q];   // rows 4q..4q+3

    // ---- epilogue: agg = acc/l, LDS round-trip to A-layout, @W_lin^T, sigmoid
    unsigned short* aggl = &aggLDS[w][0][0];   // stride 72
    #pragma unroll
    for (int nt = 0; nt < 4; ++nt)
        #pragma unroll
        for (int r = 0; r < 4; ++r)
            aggl[(q * 4 + r) * 72 + nt * 16 + i15] = f2bf(acc[nt][r] / lsq[r]);

    f32x4 d2[4] = {};
    #pragma unroll
    for (int s = 0; s < 2; ++s) {
        bf16x8 af = *(const bf16x8*)&aggl[i15 * 72 + s * 32 + q * 8];
        #pragma unroll
        for (int nt = 0; nt < 4; ++nt) {
            const float* wp = Wlin + (size_t)(nt * 16 + i15) * C_ + s * 32 + q * 8;
            f32x4 w0 = *(const f32x4*)wp;
            f32x4 w1 = *(const f32x4*)(wp + 4);
            bf16x8 bfr;
            #pragma unroll
            for (int jj = 0; jj < 4; ++jj) { bfr[jj] = (__bf16)w0[jj]; bfr[4 + jj] = (__bf16)w1[jj]; }
            d2[nt] = __builtin_amdgcn_mfma_f32_16x16x32_bf16(af, bfr, d2[nt], 0, 0, 0);
        }
    }
    float* orow = out + ((size_t)bp * N_ + ibase) * C_;
    #pragma unroll
    for (int nt = 0; nt < 4; ++nt)
        #pragma unroll
        for (int r = 0; r < 4; ++r)
            orow[(size_t)(q * 4 + r) * C_ + nt * 16 + i15] =
                1.f / (1.f + __expf(-d2[nt][r]));
}

extern "C" void kernel_launch(void* const* d_in, const int* in_sizes, int n_in,
                              void* d_out, int out_size, void* d_ws, size_t ws_size,
                              hipStream_t stream) {
    const float* x    = (const float*)d_in[0];
    const float* Ag   = (const float*)d_in[1];
    const float* Wemb = (const float*)d_in[2];
    const float* a1   = (const float*)d_in[3];
    const float* a2   = (const float*)d_in[4];
    const float* Wlin = (const float*)d_in[5];
    float* out  = (float*)d_out;
    float* outA = out + (size_t)BP_ * N_ * C_;   // tuple output #2: A passthrough

    // ws layout (~6.7 MB total)
    float* s1g = (float*)d_ws;                               // 48K f32
    float* s2g = s1g + BP_ * N_;                             // 48K f32
    float* M2part = s2g + BP_ * N_;                          // 48*64 f32
    unsigned short* xP = (unsigned short*)(M2part + BP_ * 64);   // 6.3MB bf16

    gat_pre<<<dim3(16, BP_), dim3(256), 0, stream>>>(x, Wemb, a1, a2,
                                                     s1g, s2g, xP, M2part);
    gat_fused<<<dim3(16, BP_), dim3(256), 0, stream>>>(Ag, outA, xP, s1g, s2g,
                                                       M2part, Wlin, out);
}